// Round 13
// baseline (106.866 us; speedup 1.0000x reference)
//
#include <hip/hip_runtime.h>
#include <hip/hip_bf16.h>
#include <stdint.h>
#include <stddef.h>

// ---------------------------------------------------------------------------
// MyConv2D fixed-point conv (Width=8), valid 3x3, NHWC, + bias + ReLU.
// R13: R9 structure (best: conv 70 us) with wave-tile 64x64 -> 32x64:
//   512-thr blocks, 8 waves (4M x 2N). Per-wave acc 64->32 regs => total
//   ~100-110, __launch_bounds__(512,4) caps 128 (16 waves/CU, 2 blocks).
//   Doubles resident waves at IDENTICAL per-CU traffic (B, LDS, MFMA all
//   unchanged) -> independent-block TLP hides the per-tile drain latency
//   that R3-R12 scheduling could not.
// Proven pieces kept verbatim: BK=64 A-only LDS double-buffer (32 KB),
// global_load_lds w16 with pre-swizzled source + XOR ds_read (0 conflicts,
// 128 B row stride class), fragment-ordered B global->VGPR (L2-hot 576 KB),
// one __syncthreads per tile, bijective XCD-chunked block swizzle.
// Exactness: quantized values a/256, |a|<=256 (bf16-exact); partial sums are
// integer multiples of 2^-16 << 2^24 -> fp32 MFMA accumulation exact.
// ---------------------------------------------------------------------------

typedef float  f32x4  __attribute__((ext_vector_type(4)));
typedef short  bf16x8 __attribute__((ext_vector_type(8)));

#define N_IMG 32
#define H_IN 56
#define W_IN 56
#define C_IN 128
#define F_OUT 256
#define OHW 54
#define M_TOTAL (N_IMG * OHW * OHW)   // 93312 = 729 * 128
#define BM 128
#define BN 128
#define BK 64

__device__ __forceinline__ unsigned short quant_to_bf16(float x) {
    float a = rintf(x * 256.0f);                 // half-to-even == jnp.round
    a = fminf(fmaxf(a, -256.0f), 256.0f);
    float q = a * 0.00390625f;                   // exact in bf16
    union { float f; unsigned int u; } cv; cv.f = q;
    return (unsigned short)(cv.u >> 16);
}

__device__ __forceinline__ void async_copy16(const unsigned short* g, unsigned short* l) {
    __builtin_amdgcn_global_load_lds(
        (const __attribute__((address_space(1))) unsigned int*)g,
        (__attribute__((address_space(3))) unsigned int*)l, 16, 0, 0);
}

__global__ __launch_bounds__(256) void quant_x_kernel(
        const float* __restrict__ x, unsigned short* __restrict__ xq) {
    int i = (blockIdx.x * 256 + threadIdx.x) * 4;
    float4 v = *reinterpret_cast<const float4*>(x + i);
    ushort4 o;
    o.x = quant_to_bf16(v.x);
    o.y = quant_to_bf16(v.y);
    o.z = quant_to_bf16(v.z);
    o.w = quant_to_bf16(v.w);
    *reinterpret_cast<ushort4*>(xq + i) = o;
}

// w (3,3,128,256) -> wpf in MFMA-B fragment order (same as R9):
//   idx = ((((kk*2 + hf)*2 + ks)*16 + g)*64 + l)*8 + j
//   element: f = g*16 + (l&15); c = hf*64 + ks*32 + (l>>4)*8 + j; tap kk
__global__ __launch_bounds__(256) void quant_w_kernel(
        const float* __restrict__ w, unsigned short* __restrict__ wpf) {
    int idx = blockIdx.x * 256 + threadIdx.x;     // 294912 total
    int j  = idx & 7;
    int l  = (idx >> 3) & 63;
    int g  = (idx >> 9) & 15;
    int ks = (idx >> 13) & 1;
    int hf = (idx >> 14) & 1;
    int kk = idx >> 15;
    int f  = g * 16 + (l & 15);
    int c  = hf * 64 + ks * 32 + (l >> 4) * 8 + j;
    wpf[idx] = quant_to_bf16(w[(kk * C_IN + c) * F_OUT + f]);
}

__global__ __launch_bounds__(512, 4) void conv_kernel(
        const unsigned short* __restrict__ xq,   // [32][56][56][128] bf16
        const unsigned short* __restrict__ wpf,  // fragment-ordered B
        const float* __restrict__ bias,          // [54][54][256]
        float* __restrict__ out)                 // [93312][256]
{
    __shared__ __attribute__((aligned(16))) unsigned short Alds[2][BM * BK]; // 32 KB

    const int tid  = threadIdx.x;
    const int wave = tid >> 6;
    const int lane = tid & 63;

    // bijective XCD-chunked swizzle: nwg=1458 = 8*182 + 2 (m204)
    int L;
    {
        int bid = blockIdx.x;
        int xcd = bid & 7, idx = bid >> 3;
        L = (xcd < 2) ? xcd * 183 + idx : 366 + (xcd - 2) * 182 + idx;
    }
    const int mb = L >> 1;          // consecutive L pairs share identical A
    const int nb = L & 1;
    const int m0 = mb * BM;
    const int wr = wave >> 1;       // 0..3 (32-row M quarter)
    const int wc = wave & 1;        // 0..1 (64-col f slice)

    // ---- A staging geometry (512 thr, 2 chunks/thread) ----
    // chunk c = 512r + tid; row = c>>3 = 64r + (tid>>3); slot = tid&7
    // source chunk = slot ^ (row&7) = (tid&7) ^ ((tid>>3)&7)  (64r == 0 mod 8)
    const int sw   = (tid & 7) ^ ((tid >> 3) & 7);
    const int dstc = tid & ~63;                   // wave-uniform lane-block

    const unsigned short* a_base[2];
#pragma unroll
    for (int r = 0; r < 2; ++r) {
        int m = m0 + 64 * r + (tid >> 3);
        int n_img = m / (OHW * OHW);
        int rem   = m % (OHW * OHW);
        int oh = rem / OHW, ow = rem % OHW;
        a_base[r] = xq + (size_t)((n_img * H_IN + oh) * W_IN + ow) * C_IN + sw * 8;
    }

    // stage tile t into buffer Ab: 2 gloads/thread (16B each)
    auto stageA = [&](int t, unsigned short* Ab) {
        int kk = t >> 1, hf = t & 1;
        int kh = (kk * 43) >> 7, kw = kk - 3 * kh;   // kk/3, kk%3 for kk<=8
        int aoff = (kh * W_IN + kw) * C_IN + hf * 64;
#pragma unroll
        for (int r = 0; r < 2; ++r)
            async_copy16(a_base[r] + aoff, Ab + (512 * r + dstc) * 8);
    };

    // ---- B fragment loads: single sets per ks, reloaded after last use ----
    const unsigned short* b_base = wpf + (size_t)(nb * 8 + wc * 4) * 512 + lane * 8;

    bf16x8 bP[4], bQ[4];           // bP = ks0 frags, bQ = ks1 frags
    auto loadB_P = [&](int t) {
#pragma unroll
        for (int ni = 0; ni < 4; ++ni)
            bP[ni] = *reinterpret_cast<const bf16x8*>(
                b_base + t * 16384 + ni * 512);
    };
    auto loadB_Q = [&](int t) {
#pragma unroll
        for (int ni = 0; ni < 4; ++ni)
            bQ[ni] = *reinterpret_cast<const bf16x8*>(
                b_base + t * 16384 + 8192 + ni * 512);
    };

    // ---- fragment read geometry (A from LDS, swizzled) ----
    const int mr = lane & 15;
    const int lq = lane >> 4;

    f32x4 acc[2][4];
#pragma unroll
    for (int i = 0; i < 2; ++i)
#pragma unroll
        for (int j = 0; j < 4; ++j) acc[i][j] = (f32x4)(0.0f);

    auto computeKS0 = [&](const unsigned short* Ab) {   // uses bP
        const int ch = ((lq ^ (mr & 7)) * 8);
        bf16x8 af[2];
#pragma unroll
        for (int mi = 0; mi < 2; ++mi)
            af[mi] = *reinterpret_cast<const bf16x8*>(
                Ab + (wr * 32 + mi * 16 + mr) * BK + ch);
#pragma unroll
        for (int mi = 0; mi < 2; ++mi)
#pragma unroll
            for (int ni = 0; ni < 4; ++ni)
                acc[mi][ni] = __builtin_amdgcn_mfma_f32_16x16x32_bf16(
                    af[mi], bP[ni], acc[mi][ni], 0, 0, 0);
    };
    auto computeKS1 = [&](const unsigned short* Ab) {   // uses bQ
        const int ch = (((4 + lq) ^ (mr & 7)) * 8);
        bf16x8 af[2];
#pragma unroll
        for (int mi = 0; mi < 2; ++mi)
            af[mi] = *reinterpret_cast<const bf16x8*>(
                Ab + (wr * 32 + mi * 16 + mr) * BK + ch);
#pragma unroll
        for (int mi = 0; mi < 2; ++mi)
#pragma unroll
            for (int ni = 0; ni < 4; ++ni)
                acc[mi][ni] = __builtin_amdgcn_mfma_f32_16x16x32_bf16(
                    af[mi], bQ[ni], acc[mi][ni], 0, 0, 0);
    };

    // ---- prologue ----
    stageA(0, Alds[0]);
    loadB_P(0);
    loadB_Q(0);
    __syncthreads();                       // drain tile-0 A+B

    // ---- main loop: 1 barrier/tile; B sets reloaded right after last use
#pragma unroll 1
    for (int t = 0; t < 17; ++t) {
        unsigned short* cur = Alds[t & 1];
        stageA(t + 1, Alds[(t + 1) & 1]);  // HBM: full-tile latency cover
        computeKS0(cur);                   // reads bP
        loadB_P(t + 1);                    // overwrite bP (next use: after bar)
        computeKS1(cur);                   // reads bQ
        loadB_Q(t + 1);                    // overwrite bQ
        __syncthreads();                   // implicit vmcnt(0): t+1 landed
    }
    computeKS0(Alds[1]);                   // tile 17 (17&1 = 1)
    computeKS1(Alds[1]);

    // ---- epilogue: quantize, bias, ReLU ----
    const int fcol0 = nb * BN + wc * 64 + mr;
#pragma unroll
    for (int mi = 0; mi < 2; ++mi) {
#pragma unroll
        for (int rr = 0; rr < 4; ++rr) {
            const int m = m0 + wr * 32 + mi * 16 + lq * 4 + rr;
            const float* brow = bias + (size_t)(m % (OHW * OHW)) * F_OUT;
            float* orow = out + (size_t)m * F_OUT;
#pragma unroll
            for (int ni = 0; ni < 4; ++ni) {
                float v = acc[mi][ni][rr];
                float t = rintf(v * 256.0f);
                t = fminf(fmaxf(t, -256.0f), 256.0f);
                float o = t * 0.00390625f + brow[fcol0 + ni * 16];
                orow[fcol0 + ni * 16] = fmaxf(o, 0.0f);
            }
        }
    }
}

extern "C" void kernel_launch(void* const* d_in, const int* in_sizes, int n_in,
                              void* d_out, int out_size, void* d_ws, size_t ws_size,
                              hipStream_t stream) {
    (void)in_sizes; (void)n_in; (void)out_size;
    const float* x    = (const float*)d_in[0];
    const float* w    = (const float*)d_in[1];
    const float* bias = (const float*)d_in[2];
    float* out        = (float*)d_out;

    const size_t x_elems = (size_t)N_IMG * H_IN * W_IN * C_IN;
    const size_t w_elems = (size_t)9 * F_OUT * C_IN;
    const size_t xq_bytes = x_elems * sizeof(unsigned short);  // 16B-aligned
    const size_t need = xq_bytes + w_elems * sizeof(unsigned short);
    if (ws_size < need) return;

    unsigned short* xq  = (unsigned short*)d_ws;
    unsigned short* wpf = (unsigned short*)((char*)d_ws + xq_bytes);

    quant_x_kernel<<<(int)(x_elems / (256 * 4)), 256, 0, stream>>>(x, xq);
    quant_w_kernel<<<(int)(w_elems / 256), 256, 0, stream>>>(w, wpf);
    conv_kernel<<<(M_TOTAL / BM) * 2, 512, 0, stream>>>(xq, wpf, bias, out);
}

// Round 14
// 87.401 us; speedup vs baseline: 1.2227x; 1.2227x over previous
//
#include <hip/hip_runtime.h>
#include <hip/hip_bf16.h>
#include <stdint.h>
#include <stddef.h>

// ---------------------------------------------------------------------------
// MyConv2D fixed-point conv (Width=8), valid 3x3, NHWC, + bias + ReLU.
// R14: R9 structure with BM=256 (512 thr, 8 waves 4Mx2N, 64x64/wave = R9's
// proven wave geometry). Why: R13 showed B's L2 stream is first-order
// (doubling it cost 26 us); BM=256 HALVES it (365 vs 729 M-blocks x 576 KB
// = 420 MB total) and doubles MFMA work per barrier/drain event.
// Reg budget via R13's proven single-set B trick (bP/bQ reloaded right after
// last use): acc 64 AGPR + ~64 VGPR fits __launch_bounds__(512,4) = 128.
// Proven pieces verbatim: BK=64 A-only LDS dbuf (64 KB), global_load_lds w16
// pre-swizzled source + XOR ds_read (0-conflict classes from R9/R13),
// fragment-ordered B (L2-hot), 1 barrier/tile, m204 bijective XCD swizzle
// (730 = 8*91+2). Tail: 1 half-padded block (clamped staging, guarded
// stores).
// Exactness: quantized values a/256, |a|<=256 (bf16-exact); partial sums are
// integer multiples of 2^-16 << 2^24 -> fp32 MFMA accumulation exact.
// ---------------------------------------------------------------------------

typedef float  f32x4  __attribute__((ext_vector_type(4)));
typedef short  bf16x8 __attribute__((ext_vector_type(8)));

#define N_IMG 32
#define H_IN 56
#define W_IN 56
#define C_IN 128
#define F_OUT 256
#define OHW 54
#define M_TOTAL (N_IMG * OHW * OHW)   // 93312
#define BM 256
#define BN 128
#define BK 64
#define NMB ((M_TOTAL + BM - 1) / BM)  // 365
#define NWG (NMB * 2)                  // 730 = 8*91 + 2

__device__ __forceinline__ unsigned short quant_to_bf16(float x) {
    float a = rintf(x * 256.0f);                 // half-to-even == jnp.round
    a = fminf(fmaxf(a, -256.0f), 256.0f);
    float q = a * 0.00390625f;                   // exact in bf16
    union { float f; unsigned int u; } cv; cv.f = q;
    return (unsigned short)(cv.u >> 16);
}

__device__ __forceinline__ void async_copy16(const unsigned short* g, unsigned short* l) {
    __builtin_amdgcn_global_load_lds(
        (const __attribute__((address_space(1))) unsigned int*)g,
        (__attribute__((address_space(3))) unsigned int*)l, 16, 0, 0);
}

__global__ __launch_bounds__(256) void quant_x_kernel(
        const float* __restrict__ x, unsigned short* __restrict__ xq) {
    int i = (blockIdx.x * 256 + threadIdx.x) * 4;
    float4 v = *reinterpret_cast<const float4*>(x + i);
    ushort4 o;
    o.x = quant_to_bf16(v.x);
    o.y = quant_to_bf16(v.y);
    o.z = quant_to_bf16(v.z);
    o.w = quant_to_bf16(v.w);
    *reinterpret_cast<ushort4*>(xq + i) = o;
}

// w (3,3,128,256) -> wpf in MFMA-B fragment order (same as R9/R13):
//   idx = ((((kk*2 + hf)*2 + ks)*16 + g)*64 + l)*8 + j
//   element: f = g*16 + (l&15); c = hf*64 + ks*32 + (l>>4)*8 + j; tap kk
__global__ __launch_bounds__(256) void quant_w_kernel(
        const float* __restrict__ w, unsigned short* __restrict__ wpf) {
    int idx = blockIdx.x * 256 + threadIdx.x;     // 294912 total
    int j  = idx & 7;
    int l  = (idx >> 3) & 63;
    int g  = (idx >> 9) & 15;
    int ks = (idx >> 13) & 1;
    int hf = (idx >> 14) & 1;
    int kk = idx >> 15;
    int f  = g * 16 + (l & 15);
    int c  = hf * 64 + ks * 32 + (l >> 4) * 8 + j;
    wpf[idx] = quant_to_bf16(w[(kk * C_IN + c) * F_OUT + f]);
}

__global__ __launch_bounds__(512, 4) void conv_kernel(
        const unsigned short* __restrict__ xq,   // [32][56][56][128] bf16
        const unsigned short* __restrict__ wpf,  // fragment-ordered B
        const float* __restrict__ bias,          // [54][54][256]
        float* __restrict__ out)                 // [93312][256]
{
    __shared__ __attribute__((aligned(16))) unsigned short Alds[2][BM * BK]; // 64 KB

    const int tid  = threadIdx.x;
    const int wave = tid >> 6;
    const int lane = tid & 63;

    // bijective XCD-chunked swizzle: nwg=730 = 8*91 + 2 (m204)
    int L;
    {
        int bid = blockIdx.x;
        int xcd = bid & 7, idx = bid >> 3;
        L = (xcd < 2) ? xcd * 92 + idx : 184 + (xcd - 2) * 91 + idx;
    }
    const int mb = L >> 1;          // consecutive L pairs share identical A
    const int nb = L & 1;
    const int m0 = mb * BM;
    const int wr = wave >> 1;       // 0..3 (64-row M quarter)
    const int wc = wave & 1;        // 0..1 (64-col f slice)

    // ---- A staging geometry (512 thr, 4 chunks/thread) ----
    // chunk c = 512r + tid; row = c>>3 = 64r + (tid>>3); slot = tid&7
    // source chunk = slot ^ (row&7) = (tid&7) ^ ((tid>>3)&7)  (64r == 0 mod 8)
    const int sw   = (tid & 7) ^ ((tid >> 3) & 7);
    const int dstc = tid & ~63;                   // wave-uniform lane-block

    const unsigned short* a_base[4];
#pragma unroll
    for (int r = 0; r < 4; ++r) {
        int m = m0 + 64 * r + (tid >> 3);
        if (m > M_TOTAL - 1) m = M_TOTAL - 1;     // tail block clamp
        int n_img = m / (OHW * OHW);
        int rem   = m % (OHW * OHW);
        int oh = rem / OHW, ow = rem % OHW;
        a_base[r] = xq + (size_t)((n_img * H_IN + oh) * W_IN + ow) * C_IN + sw * 8;
    }

    // stage tile t into buffer Ab: 4 gloads/thread (16B each), 32 KB total
    auto stageA = [&](int t, unsigned short* Ab) {
        int kk = t >> 1, hf = t & 1;
        int kh = (kk * 43) >> 7, kw = kk - 3 * kh;   // kk/3, kk%3 for kk<=8
        int aoff = (kh * W_IN + kw) * C_IN + hf * 64;
#pragma unroll
        for (int r = 0; r < 4; ++r)
            async_copy16(a_base[r] + aoff, Ab + (512 * r + dstc) * 8);
    };

    // ---- B fragment loads: single set per ks, reloaded after last use ----
    const unsigned short* b_base = wpf + (size_t)(nb * 8 + wc * 4) * 512 + lane * 8;

    bf16x8 bP[4], bQ[4];           // bP = ks0 frags, bQ = ks1 frags
    auto loadB_P = [&](int t) {
#pragma unroll
        for (int ni = 0; ni < 4; ++ni)
            bP[ni] = *reinterpret_cast<const bf16x8*>(
                b_base + t * 16384 + ni * 512);
    };
    auto loadB_Q = [&](int t) {
#pragma unroll
        for (int ni = 0; ni < 4; ++ni)
            bQ[ni] = *reinterpret_cast<const bf16x8*>(
                b_base + t * 16384 + 8192 + ni * 512);
    };

    // ---- fragment read geometry (A from LDS, swizzled; R9 class) ----
    const int mr = lane & 15;
    const int lq = lane >> 4;

    f32x4 acc[4][4];
#pragma unroll
    for (int i = 0; i < 4; ++i)
#pragma unroll
        for (int j = 0; j < 4; ++j) acc[i][j] = (f32x4)(0.0f);

    auto computeKS0 = [&](const unsigned short* Ab) {   // uses bP
        const int ch = ((lq ^ (mr & 7)) * 8);
        bf16x8 af[4];
#pragma unroll
        for (int mi = 0; mi < 4; ++mi)
            af[mi] = *reinterpret_cast<const bf16x8*>(
                Ab + (wr * 64 + mi * 16 + mr) * BK + ch);
#pragma unroll
        for (int mi = 0; mi < 4; ++mi)
#pragma unroll
            for (int ni = 0; ni < 4; ++ni)
                acc[mi][ni] = __builtin_amdgcn_mfma_f32_16x16x32_bf16(
                    af[mi], bP[ni], acc[mi][ni], 0, 0, 0);
    };
    auto computeKS1 = [&](const unsigned short* Ab) {   // uses bQ
        const int ch = (((4 + lq) ^ (mr & 7)) * 8);
        bf16x8 af[4];
#pragma unroll
        for (int mi = 0; mi < 4; ++mi)
            af[mi] = *reinterpret_cast<const bf16x8*>(
                Ab + (wr * 64 + mi * 16 + mr) * BK + ch);
#pragma unroll
        for (int mi = 0; mi < 4; ++mi)
#pragma unroll
            for (int ni = 0; ni < 4; ++ni)
                acc[mi][ni] = __builtin_amdgcn_mfma_f32_16x16x32_bf16(
                    af[mi], bQ[ni], acc[mi][ni], 0, 0, 0);
    };

    // ---- prologue ----
    stageA(0, Alds[0]);
    loadB_P(0);
    loadB_Q(0);
    __syncthreads();                       // drain tile-0 A+B

    // ---- main loop: 1 barrier/tile; B sets reloaded right after last use
#pragma unroll 1
    for (int t = 0; t < 17; ++t) {
        unsigned short* cur = Alds[t & 1];
        stageA(t + 1, Alds[(t + 1) & 1]);  // HBM/L2: full-tile latency cover
        computeKS0(cur);                   // reads bP
        loadB_P(t + 1);                    // overwrite bP (next use after bar)
        computeKS1(cur);                   // reads bQ
        loadB_Q(t + 1);                    // overwrite bQ
        __syncthreads();                   // implicit vmcnt(0): t+1 landed
    }
    computeKS0(Alds[1]);                   // tile 17 (17&1 = 1)
    computeKS1(Alds[1]);

    // ---- epilogue: quantize, bias, ReLU (guard tail rows) ----
    const int fcol0 = nb * BN + wc * 64 + mr;
#pragma unroll
    for (int mi = 0; mi < 4; ++mi) {
#pragma unroll
        for (int rr = 0; rr < 4; ++rr) {
            const int m = m0 + wr * 64 + mi * 16 + lq * 4 + rr;
            if (m < M_TOTAL) {
                const float* brow = bias + (size_t)(m % (OHW * OHW)) * F_OUT;
                float* orow = out + (size_t)m * F_OUT;
#pragma unroll
                for (int ni = 0; ni < 4; ++ni) {
                    float v = acc[mi][ni][rr];
                    float t = rintf(v * 256.0f);
                    t = fminf(fmaxf(t, -256.0f), 256.0f);
                    float o = t * 0.00390625f + brow[fcol0 + ni * 16];
                    orow[fcol0 + ni * 16] = fmaxf(o, 0.0f);
                }
            }
        }
    }
}

extern "C" void kernel_launch(void* const* d_in, const int* in_sizes, int n_in,
                              void* d_out, int out_size, void* d_ws, size_t ws_size,
                              hipStream_t stream) {
    (void)in_sizes; (void)n_in; (void)out_size;
    const float* x    = (const float*)d_in[0];
    const float* w    = (const float*)d_in[1];
    const float* bias = (const float*)d_in[2];
    float* out        = (float*)d_out;

    const size_t x_elems = (size_t)N_IMG * H_IN * W_IN * C_IN;
    const size_t w_elems = (size_t)9 * F_OUT * C_IN;
    const size_t xq_bytes = x_elems * sizeof(unsigned short);  // 16B-aligned
    const size_t need = xq_bytes + w_elems * sizeof(unsigned short);
    if (ws_size < need) return;

    unsigned short* xq  = (unsigned short*)d_ws;
    unsigned short* wpf = (unsigned short*)((char*)d_ws + xq_bytes);

    quant_x_kernel<<<(int)(x_elems / (256 * 4)), 256, 0, stream>>>(x, xq);
    quant_w_kernel<<<(int)(w_elems / 256), 256, 0, stream>>>(w, wpf);
    conv_kernel<<<NWG, 512, 0, stream>>>(xq, wpf, bias, out);
}

// Round 15
// 79.697 us; speedup vs baseline: 1.3409x; 1.0967x over previous
//
#include <hip/hip_runtime.h>
#include <hip/hip_bf16.h>
#include <stdint.h>
#include <stddef.h>

// ---------------------------------------------------------------------------
// MyConv2D fixed-point conv (Width=8), valid 3x3, NHWC, + bias + ReLU.
// R15: R9 conv kernel VERBATIM (session best: conv ~70 us, total 81.7) +
// quant_x/quant_w merged into one dispatch (one fewer launch in the graph).
// R9 structure: BM=128 BN=128 BK=64, 4 waves 2x2 (64x64/wave), A-only LDS
// double-buffer (32 KB) via global_load_lds w16 with pre-swizzled source +
// XOR ds_read (0 bank conflicts), B direct global->VGPR in fragment order
// (L2-hot 576 KB), double-buffered breg sets with loadB(t+1) before
// compute(t), one __syncthreads per tile, bijective XCD-chunked block
// swizzle (FETCH 105->60 MB, the one verified win besides the structure).
// Session evidence: schedules (R3/R4/R5/R7), occupancy (R8/R13), barrier-
// free (R11), BK=128 (R12), BM=256 (R14) all regressed or were null vs R9;
// R9 sits at the m97-structure's measured ceiling for this K/output mix.
// Exactness: quantized values a/256, |a|<=256 (bf16-exact); partial sums are
// integer multiples of 2^-16 << 2^24 -> fp32 MFMA accumulation exact.
// ---------------------------------------------------------------------------

typedef float  f32x4  __attribute__((ext_vector_type(4)));
typedef short  bf16x8 __attribute__((ext_vector_type(8)));

#define N_IMG 32
#define H_IN 56
#define W_IN 56
#define C_IN 128
#define F_OUT 256
#define OHW 54
#define M_TOTAL (N_IMG * OHW * OHW)   // 93312 = 729 * 128
#define BM 128
#define BN 128
#define BK 64
#define XBLOCKS 12544                  // x_elems / (256*4)
#define WBLOCKS 1152                   // w_elems / 256

__device__ __forceinline__ unsigned short quant_to_bf16(float x) {
    float a = rintf(x * 256.0f);                 // half-to-even == jnp.round
    a = fminf(fmaxf(a, -256.0f), 256.0f);
    float q = a * 0.00390625f;                   // exact in bf16
    union { float f; unsigned int u; } cv; cv.f = q;
    return (unsigned short)(cv.u >> 16);
}

__device__ __forceinline__ void async_copy16(const unsigned short* g, unsigned short* l) {
    __builtin_amdgcn_global_load_lds(
        (const __attribute__((address_space(1))) unsigned int*)g,
        (__attribute__((address_space(3))) unsigned int*)l, 16, 0, 0);
}

// Merged quantization pass: blocks [0, XBLOCKS) quantize x (float4/thread);
// blocks [XBLOCKS, XBLOCKS+WBLOCKS) quantize + permute w into MFMA-B
// fragment order: idx = ((((kk*2+hf)*2+ks)*16+g)*64+l)*8+j with
// f = g*16 + (l&15); c = hf*64 + ks*32 + (l>>4)*8 + j; tap kk.
__global__ __launch_bounds__(256) void quant_kernel(
        const float* __restrict__ x,  unsigned short* __restrict__ xq,
        const float* __restrict__ w,  unsigned short* __restrict__ wpf) {
    const int bid = blockIdx.x;
    if (bid < XBLOCKS) {
        int i = (bid * 256 + threadIdx.x) * 4;
        float4 v = *reinterpret_cast<const float4*>(x + i);
        ushort4 o;
        o.x = quant_to_bf16(v.x);
        o.y = quant_to_bf16(v.y);
        o.z = quant_to_bf16(v.z);
        o.w = quant_to_bf16(v.w);
        *reinterpret_cast<ushort4*>(xq + i) = o;
    } else {
        int idx = (bid - XBLOCKS) * 256 + threadIdx.x;   // 294912 total
        int j  = idx & 7;
        int l  = (idx >> 3) & 63;
        int g  = (idx >> 9) & 15;
        int ks = (idx >> 13) & 1;
        int hf = (idx >> 14) & 1;
        int kk = idx >> 15;
        int f  = g * 16 + (l & 15);
        int c  = hf * 64 + ks * 32 + (l >> 4) * 8 + j;
        wpf[idx] = quant_to_bf16(w[(kk * C_IN + c) * F_OUT + f]);
    }
}

__global__ __launch_bounds__(256, 2) void conv_kernel(
        const unsigned short* __restrict__ xq,   // [32][56][56][128] bf16
        const unsigned short* __restrict__ wpf,  // fragment-ordered B
        const float* __restrict__ bias,          // [54][54][256]
        float* __restrict__ out)                 // [93312][256]
{
    __shared__ __attribute__((aligned(16))) unsigned short Alds[2][BM * BK]; // 32 KB

    const int tid  = threadIdx.x;
    const int wave = tid >> 6;
    const int lane = tid & 63;

    // bijective XCD-chunked swizzle: nwg=1458 = 8*182 + 2 (m204)
    int L;
    {
        int bid = blockIdx.x;
        int xcd = bid & 7, idx = bid >> 3;
        L = (xcd < 2) ? xcd * 183 + idx : 366 + (xcd - 2) * 182 + idx;
    }
    const int mb = L >> 1;          // consecutive L pairs share identical A
    const int nb = L & 1;
    const int m0 = mb * BM;
    const int wr = wave >> 1;       // 0..1
    const int wc = wave & 1;        // 0..1

    // ---- A staging geometry: chunk = r*256 + tid; row = (tid>>3) + 32r ----
    const int row0 = tid >> 3;                    // 0..31
    const int sw   = (tid & 7) ^ (row0 & 7);      // pre-swizzled source chunk
    const int dstc = (tid & ~63) * 8;             // wave-uniform dst (shorts)

    const unsigned short* a_base[4];
#pragma unroll
    for (int r = 0; r < 4; ++r) {
        int m = m0 + row0 + 32 * r;
        int n_img = m / (OHW * OHW);
        int rem   = m % (OHW * OHW);
        int oh = rem / OHW, ow = rem % OHW;
        a_base[r] = xq + (size_t)((n_img * H_IN + oh) * W_IN + ow) * C_IN + sw * 8;
    }

    auto stageA = [&](int t, unsigned short* Ab) {
        int kk = t >> 1, hf = t & 1;
        int kh = (kk * 43) >> 7, kw = kk - 3 * kh;   // kk/3, kk%3 for kk<=8
        int aoff = (kh * W_IN + kw) * C_IN + hf * 64;
#pragma unroll
        for (int r = 0; r < 4; ++r)
            async_copy16(a_base[r] + aoff, Ab + r * 2048 + dstc);
    };

    // ---- B fragment loads: contiguous 1 KB per wave per (ni,ks) ----
    const unsigned short* b_base = wpf + (size_t)(nb * 8 + wc * 4) * 512 + lane * 8;

    bf16x8 bregA[4][2], bregB[4][2];   // two named sets (rule #20)
    auto loadB_A = [&](int t) {
#pragma unroll
        for (int ni = 0; ni < 4; ++ni)
#pragma unroll
            for (int ks = 0; ks < 2; ++ks)
                bregA[ni][ks] = *reinterpret_cast<const bf16x8*>(
                    b_base + t * 16384 + ks * 8192 + ni * 512);
    };
    auto loadB_B = [&](int t) {
#pragma unroll
        for (int ni = 0; ni < 4; ++ni)
#pragma unroll
            for (int ks = 0; ks < 2; ++ks)
                bregB[ni][ks] = *reinterpret_cast<const bf16x8*>(
                    b_base + t * 16384 + ks * 8192 + ni * 512);
    };

    // ---- fragment read geometry (A from LDS, swizzled) ----
    const int mr = lane & 15;
    const int lq = lane >> 4;

    f32x4 acc[4][4];
#pragma unroll
    for (int i = 0; i < 4; ++i)
#pragma unroll
        for (int j = 0; j < 4; ++j) acc[i][j] = (f32x4)(0.0f);

    auto computeA = [&](const unsigned short* Ab) {   // uses bregA
#pragma unroll
        for (int ks = 0; ks < 2; ++ks) {
            const int ch = (((ks * 4 + lq) ^ (mr & 7)) * 8);
            bf16x8 af[4];
#pragma unroll
            for (int mi = 0; mi < 4; ++mi)
                af[mi] = *reinterpret_cast<const bf16x8*>(
                    Ab + (wr * 64 + mi * 16 + mr) * BK + ch);
#pragma unroll
            for (int mi = 0; mi < 4; ++mi)
#pragma unroll
                for (int ni = 0; ni < 4; ++ni)
                    acc[mi][ni] = __builtin_amdgcn_mfma_f32_16x16x32_bf16(
                        af[mi], bregA[ni][ks], acc[mi][ni], 0, 0, 0);
        }
    };
    auto computeB = [&](const unsigned short* Ab) {   // uses bregB
#pragma unroll
        for (int ks = 0; ks < 2; ++ks) {
            const int ch = (((ks * 4 + lq) ^ (mr & 7)) * 8);
            bf16x8 af[4];
#pragma unroll
            for (int mi = 0; mi < 4; ++mi)
                af[mi] = *reinterpret_cast<const bf16x8*>(
                    Ab + (wr * 64 + mi * 16 + mr) * BK + ch);
#pragma unroll
            for (int mi = 0; mi < 4; ++mi)
#pragma unroll
                for (int ni = 0; ni < 4; ++ni)
                    acc[mi][ni] = __builtin_amdgcn_mfma_f32_16x16x32_bf16(
                        af[mi], bregB[ni][ks], acc[mi][ni], 0, 0, 0);
        }
    };

    // ---- prologue ----
    stageA(0, Alds[0]);
    loadB_A(0);
    __syncthreads();                       // drain tile-0 A+B

    // ---- 2-phase main loop: stage/load(t+1) overlapped with compute(t) ----
#pragma unroll 1
    for (int tp = 0; tp < 8; ++tp) {
        stageA(2 * tp + 1, Alds[1]);
        loadB_B(2 * tp + 1);
        computeA(Alds[0]);
        __syncthreads();                   // implicit vmcnt(0): t+1 data landed
        stageA(2 * tp + 2, Alds[0]);
        loadB_A(2 * tp + 2);
        computeB(Alds[1]);
        __syncthreads();
    }
    stageA(17, Alds[1]);
    loadB_B(17);
    computeA(Alds[0]);
    __syncthreads();
    computeB(Alds[1]);                     // last tile

    // ---- epilogue: quantize, bias, ReLU ----
    const int fcol0 = nb * BN + wc * 64 + mr;
#pragma unroll
    for (int mi = 0; mi < 4; ++mi) {
#pragma unroll
        for (int rr = 0; rr < 4; ++rr) {
            const int m = m0 + wr * 64 + mi * 16 + lq * 4 + rr;
            const float* brow = bias + (size_t)(m % (OHW * OHW)) * F_OUT;
            float* orow = out + (size_t)m * F_OUT;
#pragma unroll
            for (int ni = 0; ni < 4; ++ni) {
                float v = acc[mi][ni][rr];
                float t = rintf(v * 256.0f);
                t = fminf(fmaxf(t, -256.0f), 256.0f);
                float o = t * 0.00390625f + brow[fcol0 + ni * 16];
                orow[fcol0 + ni * 16] = fmaxf(o, 0.0f);
            }
        }
    }
}

extern "C" void kernel_launch(void* const* d_in, const int* in_sizes, int n_in,
                              void* d_out, int out_size, void* d_ws, size_t ws_size,
                              hipStream_t stream) {
    (void)in_sizes; (void)n_in; (void)out_size;
    const float* x    = (const float*)d_in[0];
    const float* w    = (const float*)d_in[1];
    const float* bias = (const float*)d_in[2];
    float* out        = (float*)d_out;

    const size_t x_elems = (size_t)N_IMG * H_IN * W_IN * C_IN;
    const size_t w_elems = (size_t)9 * F_OUT * C_IN;
    const size_t xq_bytes = x_elems * sizeof(unsigned short);  // 16B-aligned
    const size_t need = xq_bytes + w_elems * sizeof(unsigned short);
    if (ws_size < need) return;

    unsigned short* xq  = (unsigned short*)d_ws;
    unsigned short* wpf = (unsigned short*)((char*)d_ws + xq_bytes);

    quant_kernel<<<XBLOCKS + WBLOCKS, 256, 0, stream>>>(x, xq, w, wpf);
    conv_kernel<<<(M_TOTAL / BM) * 2, 256, 0, stream>>>(xq, wpf, bias, out);
}